// Round 2
// baseline (1686.841 us; speedup 1.0000x reference)
//
#include <hip/hip_runtime.h>
#include <stdint.h>

// ---------------------------------------------------------------------------
// Fused MoE block on gfx950. Single persistent main kernel + tiny prep kernel.
// All GEMMs computed transposed (weights as MFMA A operand) so each lane owns
// exactly one token (lane&15) in every D fragment -> LN/router reductions are
// in-lane + 2 shuffles; stage-to-stage transpose is a 4-lane ds_bpermute.
// R2: one 16-token subtile per wave-iteration (was 32) to keep worst-point
// live VGPRs ~115 -> no scratch spills (R1 spilled: 2.46 GB HBM, 1158 us).
// ---------------------------------------------------------------------------

typedef __attribute__((ext_vector_type(8))) short bf16x8;  // MFMA A/B operand
typedef __attribute__((ext_vector_type(4))) float f32x4;   // MFMA C/D operand

#define MFMA16(a, b, c) __builtin_amdgcn_mfma_f32_16x16x32_bf16((a), (b), (c), 0, 0, 0)

__device__ __forceinline__ uint32_t f2bf1(float f) {  // fp32 -> bf16 bits, RNE
  uint32_t u = __float_as_uint(f);
  return (u + 0x7FFFu + ((u >> 16) & 1u)) >> 16;
}

// exact-erf GELU via Abramowitz&Stegun 7.1.26 (|err| <= 1.5e-7)
__device__ __forceinline__ float geluf(float x) {
  float ax = __builtin_fabsf(x);
  float z  = ax * 0.70710678118654752f;
  float t  = __builtin_amdgcn_rcpf(__builtin_fmaf(0.3275911f, z, 1.0f));
  float p  = __builtin_fmaf(1.061405429f, t, -1.453152027f);
  p = __builtin_fmaf(p, t, 1.421413741f);
  p = __builtin_fmaf(p, t, -0.284496736f);
  p = __builtin_fmaf(p, t, 0.254829592f);
  p = p * t;
  float e  = __builtin_amdgcn_exp2f(-1.4426950408889634f * z * z);
  float er = __builtin_fmaf(-p, e, 1.0f);  // |erf(z)|
  return __builtin_fmaf(0.5f * ax, er, 0.5f * x);
}

__device__ __forceinline__ float bperm(int ad, float a) {
  return __int_as_float(__builtin_amdgcn_ds_bpermute(ad, __float_as_int(a)));
}

// D-layout fp32 (token=lane&15, dim = mt*16 + q*4 + r)  ->  B-frag bf16
// (token=lane&15, k = c*32 + q*8 + i).  src lane = ((q&1)*2 + (i>>2))*16 + t,
// src reg = V[2c + (q>>1)][i&3].
__device__ __forceinline__ void xpose(const f32x4 (&V)[8], bf16x8 (&F)[4],
                                      int addr0, int addr1, bool qhi) {
#pragma unroll
  for (int c = 0; c < 4; ++c) {
    union { bf16x8 v; uint32_t u4[4]; } cv;
#pragma unroll
    for (int ii = 0; ii < 4; ++ii) {
      const int hi = ii >> 1;
      const int r0 = (ii & 1) * 2;
      const int ad = hi ? addr1 : addr0;
      float sa0 = qhi ? V[2 * c + 1][r0]     : V[2 * c][r0];
      float sa1 = qhi ? V[2 * c + 1][r0 + 1] : V[2 * c][r0 + 1];
      // NOTE: select BEFORE bpermute is wrong in general (source lane chooses),
      // but here qhi is uniform within each source group of 16 lanes matched by
      // ad's lane pattern only across tq; q of DEST decides reg -> must select
      // on DEST. Keep original: permute both, select after.
      float a0 = bperm(ad, V[2 * c][r0]);
      float b0 = bperm(ad, V[2 * c + 1][r0]);
      float a1 = bperm(ad, V[2 * c][r0 + 1]);
      float b1 = bperm(ad, V[2 * c + 1][r0 + 1]);
      (void)sa0; (void)sa1;
      float x0 = qhi ? b0 : a0;
      float x1 = qhi ? b1 : a1;
      cv.u4[ii] = f2bf1(x0) | (f2bf1(x1) << 16);
    }
    F[c] = cv.v;
  }
}

// ---------------------------------------------------------------------------
// prep: build bf16 A-fragment tables in ws.
// Layout (uint16 units): [0,16384) entry_w | [16384,81920) exp_w e=0..3 |
// [81920,98304) out_w.  Within a matrix: tile = mt*4+c (512 shorts), element
// lane*8+j = W[k=c*32+(lane>>4)*8+j][m=mt*16+(lane&15)].
// ---------------------------------------------------------------------------
__global__ void prep_frags(const float* __restrict__ w1,
                           const float* __restrict__ ew,
                           const float* __restrict__ ow,
                           uint16_t* __restrict__ ftab) {
  int idx = blockIdx.x * 256 + threadIdx.x;
  if (idx >= 98304) return;
  const float* mat;
  int rel;
  if (idx < 16384) { mat = w1; rel = idx; }
  else if (idx < 81920) {
    int e = (idx - 16384) >> 14;
    rel = (idx - 16384) & 16383;
    mat = ew + e * 16384;
  } else { mat = ow; rel = idx - 81920; }
  int tilei = rel >> 9;
  int ln    = (rel >> 3) & 63;
  int j     = rel & 7;
  int mt = tilei >> 2, c = tilei & 3;
  int k = c * 32 + ((ln >> 4) << 3) + j;
  int m = mt * 16 + (ln & 15);
  ftab[idx] = (uint16_t)f2bf1(mat[k * 128 + m]);
}

// ---------------------------------------------------------------------------
// main fused kernel: 256 blocks x 512 threads (8 waves), 1 block/CU
// (LDS 128 KiB caps at 1 block/CU -> 2 waves/SIMD; pin waves_per_eu so the
// allocator gets the full 256-reg budget and never spills).
// Each wave processes one 16-token subtile per iteration.
// ---------------------------------------------------------------------------
__global__ __launch_bounds__(512)
__attribute__((amdgpu_waves_per_eu(2, 2)))
void moe_main(
    const float* __restrict__ x, const float* __restrict__ eb,
    const float* __restrict__ rw, const float* __restrict__ rb,
    const float* __restrict__ expb, const float* __restrict__ lng,
    const float* __restrict__ lnb, const float* __restrict__ ob,
    const uint16_t* __restrict__ ftab, float* __restrict__ out, int ntiles) {
  extern __shared__ uint16_t lds_u16[];

  {  // stage exp_w frags -> LDS (contiguous copy)
    const uint4* src = (const uint4*)(ftab + 16384);
    uint4* dst = (uint4*)lds_u16;
    for (int i = threadIdx.x; i < 8192; i += 512) dst[i] = src[i];
  }
  __syncthreads();

  const int lane = threadIdx.x & 63;
  const int wave = threadIdx.x >> 6;
  const int q    = lane >> 4;
  const int tq   = lane & 15;
  const bool qhi = q >= 2;
  const int addr0 = ((((q & 1) << 1) << 4) + tq) << 2;  // ((q&1)*2*16+tq)*4
  const int addr1 = addr0 + 64;

  const bf16x8* w1f = (const bf16x8*)ftab;             // entry_w frags (L2)
  const bf16x8* owf = (const bf16x8*)(ftab + 81920);   // out_w frags (L2)
  const bf16x8* ef  = (const bf16x8*)lds_u16;          // exp_w frags (LDS)

  const int stride = gridDim.x * 8;
  for (int tile = blockIdx.x * 8 + wave; tile < ntiles; tile += stride) {
    const int t0 = tile * 16;

    // ---- load x as B-frags (xT), fp32 -> bf16 RNE ----
    bf16x8 xB[4];
    {
      const float* xr = x + (size_t)(t0 + tq) * 128 + q * 8;
#pragma unroll
      for (int c = 0; c < 4; ++c) {
        f32x4 v0 = *(const f32x4*)(xr + c * 32);
        f32x4 v1 = *(const f32x4*)(xr + c * 32 + 4);
        union { bf16x8 v; uint32_t u4[4]; } cv;
        cv.u4[0] = f2bf1(v0[0]) | (f2bf1(v0[1]) << 16);
        cv.u4[1] = f2bf1(v0[2]) | (f2bf1(v0[3]) << 16);
        cv.u4[2] = f2bf1(v1[0]) | (f2bf1(v1[1]) << 16);
        cv.u4[3] = f2bf1(v1[2]) | (f2bf1(v1[3]) << 16);
        xB[c] = cv.v;
      }
    }

    // ---- entry GEMM: hT = W1T @ xT ----
    f32x4 h[8];
#pragma unroll
    for (int mt = 0; mt < 8; ++mt) h[mt] = {0, 0, 0, 0};
#pragma unroll
    for (int c = 0; c < 4; ++c) {
#pragma unroll
      for (int mt = 0; mt < 8; ++mt) {
        bf16x8 a = w1f[(mt * 4 + c) * 64 + lane];
        h[mt] = MFMA16(a, xB[c], h[mt]);
      }
    }

    // ---- bias + GELU (fp32) + router logits (fp32 h, fp32 rw) ----
    float lg[4] = {0, 0, 0, 0};
#pragma unroll
    for (int mt = 0; mt < 8; ++mt) {
      f32x4 bb = *(const f32x4*)(eb + mt * 16 + q * 4);
#pragma unroll
      for (int r = 0; r < 4; ++r) {
        f32x4 rwv = *(const f32x4*)(rw + (mt * 16 + q * 4 + r) * 4);
        float v = geluf(h[mt][r] + bb[r]);
        h[mt][r] = v;
#pragma unroll
        for (int e = 0; e < 4; ++e) lg[e] = __builtin_fmaf(v, rwv[e], lg[e]);
      }
    }

    // ---- router reduce (lanes t, t^16, t^32, t^48 hold all 128 dims) + softmax
    float wgt[4];
    {
#pragma unroll
      for (int e = 0; e < 4; ++e) {
        float v = lg[e];
        v += __shfl_xor(v, 16);
        v += __shfl_xor(v, 32);
        lg[e] = v + rb[e];
      }
      float m = fmaxf(fmaxf(lg[0], lg[1]), fmaxf(lg[2], lg[3]));
      float ex0 = __builtin_amdgcn_exp2f((lg[0] - m) * 1.4426950408889634f);
      float ex1 = __builtin_amdgcn_exp2f((lg[1] - m) * 1.4426950408889634f);
      float ex2 = __builtin_amdgcn_exp2f((lg[2] - m) * 1.4426950408889634f);
      float ex3 = __builtin_amdgcn_exp2f((lg[3] - m) * 1.4426950408889634f);
      float inv = __builtin_amdgcn_rcpf(ex0 + ex1 + ex2 + ex3);
      wgt[0] = ex0 * inv; wgt[1] = ex1 * inv;
      wgt[2] = ex2 * inv; wgt[3] = ex3 * inv;
    }

    // ---- transpose h (D-layout) -> B-frags for expert GEMMs ----
    bf16x8 hB[4];
    xpose(h, hB, addr0, addr1, qhi);

    // ---- experts: eoT = WeT @ hT, GELU, LN, weighted combine ----
    f32x4 comb[8];
#pragma unroll
    for (int mt = 0; mt < 8; ++mt) comb[mt] = {0, 0, 0, 0};

#pragma unroll
    for (int e = 0; e < 4; ++e) {
      f32x4 eo[8];
#pragma unroll
      for (int mt = 0; mt < 8; ++mt) eo[mt] = {0, 0, 0, 0};
#pragma unroll
      for (int c = 0; c < 4; ++c) {
#pragma unroll
        for (int mt = 0; mt < 8; ++mt) {
          bf16x8 a = ef[(e * 32 + mt * 4 + c) * 64 + lane];
          eo[mt] = MFMA16(a, hB[c], eo[mt]);
        }
      }
      float s1 = 0.f, s2 = 0.f;
#pragma unroll
      for (int mt = 0; mt < 8; ++mt) {
        f32x4 bb = *(const f32x4*)(expb + e * 128 + mt * 16 + q * 4);
#pragma unroll
        for (int r = 0; r < 4; ++r) {
          float v = geluf(eo[mt][r] + bb[r]);
          eo[mt][r] = v;
          s1 += v;
          s2 = __builtin_fmaf(v, v, s2);
        }
      }
      s1 += __shfl_xor(s1, 16); s1 += __shfl_xor(s1, 32);
      s2 += __shfl_xor(s2, 16); s2 += __shfl_xor(s2, 32);
      float mu   = s1 * 0.0078125f;
      float var  = __builtin_fmaf(s2, 0.0078125f, -mu * mu);
      float rstd = __builtin_amdgcn_rsqf(var + 1e-5f);
      float wk   = wgt[e];
#pragma unroll
      for (int mt = 0; mt < 8; ++mt) {
        f32x4 g = *(const f32x4*)(lng + e * 128 + mt * 16 + q * 4);
        f32x4 b = *(const f32x4*)(lnb + e * 128 + mt * 16 + q * 4);
#pragma unroll
        for (int r = 0; r < 4; ++r) {
          float v = (eo[mt][r] - mu) * rstd;
          v = __builtin_fmaf(v, g[r], b[r]);
          comb[mt][r] = __builtin_fmaf(wk, v, comb[mt][r]);
        }
      }
    }

    // ---- transpose combined -> B-frags; out GEMM: outT = WoT @ combT ----
    bf16x8 cB[4];
    xpose(comb, cB, addr0, addr1, qhi);

    f32x4 oacc[8];
#pragma unroll
    for (int mt = 0; mt < 8; ++mt) oacc[mt] = {0, 0, 0, 0};
#pragma unroll
    for (int c = 0; c < 4; ++c) {
#pragma unroll
      for (int mt = 0; mt < 8; ++mt) {
        bf16x8 a = owf[(mt * 4 + c) * 64 + lane];
        oacc[mt] = MFMA16(a, cB[c], oacc[mt]);
      }
    }

    // ---- bias + store (float4, fully covering each token row) ----
#pragma unroll
    for (int mt = 0; mt < 8; ++mt) {
      f32x4 bo = *(const f32x4*)(ob + mt * 16 + q * 4);
      f32x4 v = oacc[mt] + bo;
      *(f32x4*)(out + (size_t)(t0 + tq) * 128 + mt * 16 + q * 4) = v;
    }
  }
}

extern "C" void kernel_launch(void* const* d_in, const int* in_sizes, int n_in,
                              void* d_out, int out_size, void* d_ws, size_t ws_size,
                              hipStream_t stream) {
  const float* x    = (const float*)d_in[0];
  const float* w1   = (const float*)d_in[1];
  const float* eb   = (const float*)d_in[2];
  const float* rw   = (const float*)d_in[3];
  const float* rb   = (const float*)d_in[4];
  const float* ew   = (const float*)d_in[5];
  const float* expb = (const float*)d_in[6];
  const float* lng  = (const float*)d_in[7];
  const float* lnb  = (const float*)d_in[8];
  const float* ow   = (const float*)d_in[9];
  const float* ob   = (const float*)d_in[10];
  float* out = (float*)d_out;
  uint16_t* ftab = (uint16_t*)d_ws;  // 196608 bytes used

  int ntok   = in_sizes[0] / 128;
  int ntiles = ntok / 16;

  hipLaunchKernelGGL(prep_frags, dim3(384), dim3(256), 0, stream, w1, ew, ow, ftab);

  // opt-in to 128 KiB dynamic LDS (idempotent; not a stream op)
  (void)hipFuncSetAttribute((const void*)moe_main,
                            hipFuncAttributeMaxDynamicSharedMemorySize, 131072);

  hipLaunchKernelGGL(moe_main, dim3(256), dim3(512), 131072, stream,
                     x, eb, rw, rb, expb, lng, lnb, ob,
                     (const uint16_t*)ftab, out, ntiles);
}

// Round 3
// 972.370 us; speedup vs baseline: 1.7348x; 1.7348x over previous
//
#include <hip/hip_runtime.h>
#include <stdint.h>

// ---------------------------------------------------------------------------
// Fused MoE block on gfx950.  R3 structure:
//   - weights pre-swizzled to MFMA A-frag tables in ws (prep_frags)
//   - main kernel: 512 blocks x 512 thr, 64 KiB LDS (2 x 32 KiB double buffer)
//     => 2 blocks/CU, 16 waves/CU (4/SIMD) -- R2 was latency-bound at 2/SIMD.
//   - per block-iter (128 tokens): 6 stages (entry, e0..e3, out); each stage's
//     32 KiB frag table async-staged via global_load_lds width=16 into the
//     spare buffer while the current stage computes (barrier-per-stage).
//   - all GEMMs transposed (weights = A operand) so each lane owns one token;
//     LN/router reductions = 2 shuffles; stage transpose = 4-lane bpermute.
// ---------------------------------------------------------------------------

typedef __attribute__((ext_vector_type(8))) short bf16x8;  // MFMA A/B operand
typedef __attribute__((ext_vector_type(4))) float f32x4;   // MFMA C/D operand

#define MFMA16(a, b, c) __builtin_amdgcn_mfma_f32_16x16x32_bf16((a), (b), (c), 0, 0, 0)

using gas1_u32 = __attribute__((address_space(1))) const uint32_t;
using las3_u32 = __attribute__((address_space(3))) uint32_t;

__device__ __forceinline__ uint32_t f2bf1(float f) {  // fp32 -> bf16 bits, RNE
  uint32_t u = __float_as_uint(f);
  return (u + 0x7FFFu + ((u >> 16) & 1u)) >> 16;
}

// exact-erf GELU via Abramowitz&Stegun 7.1.26 (|err| <= 1.5e-7)
__device__ __forceinline__ float geluf(float x) {
  float ax = __builtin_fabsf(x);
  float z  = ax * 0.70710678118654752f;
  float t  = __builtin_amdgcn_rcpf(__builtin_fmaf(0.3275911f, z, 1.0f));
  float p  = __builtin_fmaf(1.061405429f, t, -1.453152027f);
  p = __builtin_fmaf(p, t, 1.421413741f);
  p = __builtin_fmaf(p, t, -0.284496736f);
  p = __builtin_fmaf(p, t, 0.254829592f);
  p = p * t;
  float e  = __builtin_amdgcn_exp2f(-1.4426950408889634f * z * z);
  float er = __builtin_fmaf(-p, e, 1.0f);  // |erf(z)|
  return __builtin_fmaf(0.5f * ax, er, 0.5f * x);
}

__device__ __forceinline__ float bperm(int ad, float a) {
  return __int_as_float(__builtin_amdgcn_ds_bpermute(ad, __float_as_int(a)));
}

// D-layout fp32 (token=lane&15, dim = mt*16 + q*4 + r)  ->  B-frag bf16
// (token=lane&15, k = c*32 + q*8 + i).  src lane = ((q&1)*2 + (i>>2))*16 + t,
// src reg = V[2c + (q>>1)][i&3].  Permute both reg candidates, select on dest.
__device__ __forceinline__ void xpose(const f32x4 (&V)[8], bf16x8 (&F)[4],
                                      int addr0, int addr1, bool qhi) {
#pragma unroll
  for (int c = 0; c < 4; ++c) {
    union { bf16x8 v; uint32_t u4[4]; } cv;
#pragma unroll
    for (int ii = 0; ii < 4; ++ii) {
      const int r0 = (ii & 1) * 2;
      const int ad = (ii >> 1) ? addr1 : addr0;
      float a0 = bperm(ad, V[2 * c][r0]);
      float b0 = bperm(ad, V[2 * c + 1][r0]);
      float a1 = bperm(ad, V[2 * c][r0 + 1]);
      float b1 = bperm(ad, V[2 * c + 1][r0 + 1]);
      float x0 = qhi ? b0 : a0;
      float x1 = qhi ? b1 : a1;
      cv.u4[ii] = f2bf1(x0) | (f2bf1(x1) << 16);
    }
    F[c] = cv.v;
  }
}

// async-stage one 32 KiB frag table (contiguous) into LDS: 8 waves x 4 KiB,
// 4 x global_load_lds_dwordx4 per wave (lds dest = uniform base + lane*16).
__device__ __forceinline__ void stage32k(const uint16_t* __restrict__ g,
                                         uint16_t* l, int wave, int lane) {
  const uint8_t* gb = (const uint8_t*)g + (wave << 12) + (lane << 4);
  uint8_t* lb = (uint8_t*)l + (wave << 12);
#pragma unroll
  for (int j = 0; j < 4; ++j) {
    __builtin_amdgcn_global_load_lds((gas1_u32*)(gb + j * 1024),
                                     (las3_u32*)(lb + j * 1024), 16, 0, 0);
  }
}

// ---------------------------------------------------------------------------
// prep: build bf16 A-fragment tables in ws (uint16 units, 6 contiguous 32 KiB
// stages): [0,16384) entry_w | [16384,81920) exp_w e=0..3 | [81920,98304)
// out_w.  tile = mt*4+c (512 shorts); element lane*8+j =
// W[k=c*32+(lane>>4)*8+j][m=mt*16+(lane&15)].
// ---------------------------------------------------------------------------
__global__ void prep_frags(const float* __restrict__ w1,
                           const float* __restrict__ ew,
                           const float* __restrict__ ow,
                           uint16_t* __restrict__ ftab) {
  int idx = blockIdx.x * 256 + threadIdx.x;
  if (idx >= 98304) return;
  const float* mat;
  int rel;
  if (idx < 16384) { mat = w1; rel = idx; }
  else if (idx < 81920) {
    int e = (idx - 16384) >> 14;
    rel = (idx - 16384) & 16383;
    mat = ew + e * 16384;
  } else { mat = ow; rel = idx - 81920; }
  int tilei = rel >> 9;
  int ln    = (rel >> 3) & 63;
  int j     = rel & 7;
  int mt = tilei >> 2, c = tilei & 3;
  int k = c * 32 + ((ln >> 4) << 3) + j;
  int m = mt * 16 + (ln & 15);
  ftab[idx] = (uint16_t)f2bf1(mat[k * 128 + m]);
}

// ---------------------------------------------------------------------------
__global__ __launch_bounds__(512, 4) void moe_main(
    const float* __restrict__ x, const float* __restrict__ eb,
    const float* __restrict__ rw, const float* __restrict__ rb,
    const float* __restrict__ expb, const float* __restrict__ lng,
    const float* __restrict__ lnb, const float* __restrict__ ob,
    const uint16_t* __restrict__ ftab, float* __restrict__ out, int nbi) {
  extern __shared__ uint16_t lds_u16[];
  uint16_t* lds0 = lds_u16;
  uint16_t* lds1 = lds_u16 + 16384;

  const int lane = threadIdx.x & 63;
  const int wave = threadIdx.x >> 6;
  const int q    = lane >> 4;
  const int tq   = lane & 15;
  const bool qhi = q >= 2;
  const int addr0 = ((((q & 1) << 1) << 4) + tq) << 2;
  const int addr1 = addr0 + 64;

  stage32k(ftab, lds0, wave, lane);  // prologue: entry table -> buf0

  for (int bi = blockIdx.x; bi < nbi; bi += gridDim.x) {
    const int t0 = bi * 128 + wave * 16;

    // ---- x -> bf16 B-frags (issue global loads before the stage barrier) ----
    bf16x8 xB[4];
    {
      const float* xr = x + (size_t)(t0 + tq) * 128 + q * 8;
#pragma unroll
      for (int c = 0; c < 4; ++c) {
        f32x4 v0 = *(const f32x4*)(xr + c * 32);
        f32x4 v1 = *(const f32x4*)(xr + c * 32 + 4);
        union { bf16x8 v; uint32_t u4[4]; } cv;
        cv.u4[0] = f2bf1(v0[0]) | (f2bf1(v0[1]) << 16);
        cv.u4[1] = f2bf1(v0[2]) | (f2bf1(v0[3]) << 16);
        cv.u4[2] = f2bf1(v1[0]) | (f2bf1(v1[1]) << 16);
        cv.u4[3] = f2bf1(v1[2]) | (f2bf1(v1[3]) << 16);
        xB[c] = cv.v;
      }
    }

    // ================= stage 0: entry (buf0) =================
    __syncthreads();                           // entry table landed
    stage32k(ftab + 16384, lds1, wave, lane);  // prefetch expert0 -> buf1

    f32x4 h[8];
#pragma unroll
    for (int mt = 0; mt < 8; ++mt) h[mt] = {0, 0, 0, 0};
    {
      const bf16x8* f0 = (const bf16x8*)lds0;
#pragma unroll
      for (int c = 0; c < 4; ++c)
#pragma unroll
        for (int mt = 0; mt < 8; ++mt)
          h[mt] = MFMA16(f0[(mt * 4 + c) * 64 + lane], xB[c], h[mt]);
    }

    // bias + GELU + router logits
    float lg[4] = {0, 0, 0, 0};
#pragma unroll
    for (int mt = 0; mt < 8; ++mt) {
      f32x4 bb = *(const f32x4*)(eb + mt * 16 + q * 4);
#pragma unroll
      for (int r = 0; r < 4; ++r) {
        f32x4 rwv = *(const f32x4*)(rw + (mt * 16 + q * 4 + r) * 4);
        float v = geluf(h[mt][r] + bb[r]);
        h[mt][r] = v;
#pragma unroll
        for (int e = 0; e < 4; ++e) lg[e] = __builtin_fmaf(v, rwv[e], lg[e]);
      }
    }

    float wgt[4];
    {
#pragma unroll
      for (int e = 0; e < 4; ++e) {
        float v = lg[e];
        v += __shfl_xor(v, 16);
        v += __shfl_xor(v, 32);
        lg[e] = v + rb[e];
      }
      float m = fmaxf(fmaxf(lg[0], lg[1]), fmaxf(lg[2], lg[3]));
      float ex0 = __builtin_amdgcn_exp2f((lg[0] - m) * 1.4426950408889634f);
      float ex1 = __builtin_amdgcn_exp2f((lg[1] - m) * 1.4426950408889634f);
      float ex2 = __builtin_amdgcn_exp2f((lg[2] - m) * 1.4426950408889634f);
      float ex3 = __builtin_amdgcn_exp2f((lg[3] - m) * 1.4426950408889634f);
      float inv = __builtin_amdgcn_rcpf(ex0 + ex1 + ex2 + ex3);
      wgt[0] = ex0 * inv; wgt[1] = ex1 * inv;
      wgt[2] = ex2 * inv; wgt[3] = ex3 * inv;
    }

    bf16x8 hB[4];
    xpose(h, hB, addr0, addr1, qhi);

    // ================= stages 1..4: experts =================
    // parity: expert e computes from (e&1 ? buf0 : buf1), prefetches next
    // stage (table index e+2; e=3 -> 5 = out) into the other buffer.
    f32x4 comb[8];
#pragma unroll
    for (int mt = 0; mt < 8; ++mt) comb[mt] = {0, 0, 0, 0};

#pragma unroll
    for (int e = 0; e < 4; ++e) {
      __syncthreads();                                        // table e landed
      stage32k(ftab + (e + 2) * 16384, (e & 1) ? lds1 : lds0, wave, lane);
      const bf16x8* fe = (const bf16x8*)((e & 1) ? lds0 : lds1);

      f32x4 eo[8];
#pragma unroll
      for (int mt = 0; mt < 8; ++mt) eo[mt] = {0, 0, 0, 0};
#pragma unroll
      for (int c = 0; c < 4; ++c)
#pragma unroll
        for (int mt = 0; mt < 8; ++mt)
          eo[mt] = MFMA16(fe[(mt * 4 + c) * 64 + lane], hB[c], eo[mt]);

      float s1 = 0.f, s2 = 0.f;
#pragma unroll
      for (int mt = 0; mt < 8; ++mt) {
        f32x4 bb = *(const f32x4*)(expb + e * 128 + mt * 16 + q * 4);
#pragma unroll
        for (int r = 0; r < 4; ++r) {
          float v = geluf(eo[mt][r] + bb[r]);
          eo[mt][r] = v;
          s1 += v;
          s2 = __builtin_fmaf(v, v, s2);
        }
      }
      s1 += __shfl_xor(s1, 16); s1 += __shfl_xor(s1, 32);
      s2 += __shfl_xor(s2, 16); s2 += __shfl_xor(s2, 32);
      float mu   = s1 * 0.0078125f;
      float var  = __builtin_fmaf(s2, 0.0078125f, -mu * mu);
      float rstd = __builtin_amdgcn_rsqf(var + 1e-5f);
      float wk   = wgt[e];
#pragma unroll
      for (int mt = 0; mt < 8; ++mt) {
        f32x4 g = *(const f32x4*)(lng + e * 128 + mt * 16 + q * 4);
        f32x4 b = *(const f32x4*)(lnb + e * 128 + mt * 16 + q * 4);
#pragma unroll
        for (int r = 0; r < 4; ++r) {
          float v = (eo[mt][r] - mu) * rstd;
          v = __builtin_fmaf(v, g[r], b[r]);
          comb[mt][r] = __builtin_fmaf(wk, v, comb[mt][r]);
        }
      }
    }

    // ================= stage 5: out GEMM (buf1) =================
    __syncthreads();                   // out table landed
    stage32k(ftab, lds0, wave, lane);  // prefetch next bi's entry -> buf0

    bf16x8 cB[4];
    xpose(comb, cB, addr0, addr1, qhi);

    f32x4 oacc[8];
#pragma unroll
    for (int mt = 0; mt < 8; ++mt) oacc[mt] = {0, 0, 0, 0};
    {
      const bf16x8* fo = (const bf16x8*)lds1;
#pragma unroll
      for (int c = 0; c < 4; ++c)
#pragma unroll
        for (int mt = 0; mt < 8; ++mt)
          oacc[mt] = MFMA16(fo[(mt * 4 + c) * 64 + lane], cB[c], oacc[mt]);
    }

#pragma unroll
    for (int mt = 0; mt < 8; ++mt) {
      f32x4 bo = *(const f32x4*)(ob + mt * 16 + q * 4);
      f32x4 v = oacc[mt] + bo;
      *(f32x4*)(out + (size_t)(t0 + tq) * 128 + mt * 16 + q * 4) = v;
    }
  }
}

extern "C" void kernel_launch(void* const* d_in, const int* in_sizes, int n_in,
                              void* d_out, int out_size, void* d_ws, size_t ws_size,
                              hipStream_t stream) {
  const float* x    = (const float*)d_in[0];
  const float* w1   = (const float*)d_in[1];
  const float* eb   = (const float*)d_in[2];
  const float* rw   = (const float*)d_in[3];
  const float* rb   = (const float*)d_in[4];
  const float* ew   = (const float*)d_in[5];
  const float* expb = (const float*)d_in[6];
  const float* lng  = (const float*)d_in[7];
  const float* lnb  = (const float*)d_in[8];
  const float* ow   = (const float*)d_in[9];
  const float* ob   = (const float*)d_in[10];
  float* out = (float*)d_out;
  uint16_t* ftab = (uint16_t*)d_ws;  // 196608 bytes used

  int ntok = in_sizes[0] / 128;
  int nbi  = ntok / 128;  // 128 tokens per block-iteration

  hipLaunchKernelGGL(prep_frags, dim3(384), dim3(256), 0, stream, w1, ew, ow, ftab);

  (void)hipFuncSetAttribute((const void*)moe_main,
                            hipFuncAttributeMaxDynamicSharedMemorySize, 65536);

  hipLaunchKernelGGL(moe_main, dim3(512), dim3(512), 65536, stream,
                     x, eb, rw, rb, expb, lng, lnb, ob,
                     (const uint16_t*)ftab, out, nbi);
}